// Round 9
// baseline (136.060 us; speedup 1.0000x reference)
//
#include <hip/hip_runtime.h>
#include <hip/hip_bf16.h>

#define CIN 256
#define CRED 64
#define NB 4
#define NN 4096

typedef float v4f __attribute__((ext_vector_type(4)));
typedef short v8s __attribute__((ext_vector_type(8)));
typedef unsigned short u16;
typedef u16 u16x4 __attribute__((ext_vector_type(4)));
typedef u16 u16x8 __attribute__((ext_vector_type(8)));
typedef unsigned int u32;

#define LOG2E 1.4426950408889634f

__device__ __forceinline__ u16 f2bf(float f) {
    union { float f; u32 u; } v; v.f = f;
    u32 r = (v.u + 0x7FFFu + ((v.u >> 16) & 1u)) >> 16;  // RNE
    return (u16)r;
}
__device__ __forceinline__ float bf2f(u16 s) {
    union { u32 u; float f; } v; v.u = ((u32)s) << 16;
    return v.f;
}
// packed f32x2 -> bf16x2 (v_cvt_pk_bf16_f32 on gfx950), low half = a
__device__ __forceinline__ u32 pkbf(float a, float b) {
    float2 f; f.x = a; f.y = b;
    __hip_bfloat162 h = __float22bfloat162_rn(f);
    union { __hip_bfloat162 h; u32 u; } c; c.h = h;
    return c.u;
}
__device__ __forceinline__ v4f mfma16(v8s a, v8s b, v4f c) {
    return __builtin_amdgcn_mfma_f32_16x16x32_bf16(a, b, c, 0, 0, 0);
}
__device__ __forceinline__ float fexp2(float x) {
#if __has_builtin(__builtin_amdgcn_exp2f)
    return __builtin_amdgcn_exp2f(x);
#else
    return exp2f(x);
#endif
}

// ------------- kernel 1: QKV projection via MFMA, 3-way matrix split --------
// Grid 1536: blocks [0,512) Q, [512,1024) K, [1024,1536) V; 32 tokens/block.
// Q,K: (b,n,r) bf16 (Q scaled 0.125*log2e). V: (b,r,n) with key-permuted n
// inside each 64-tile: pos(n) = (n&15)*4 + ((n>>4)&3). Weights converted inline.
__global__ __launch_bounds__(256) void k_qkvm(const float* __restrict__ x,
                                              const float* __restrict__ Wq,
                                              const float* __restrict__ Wk,
                                              const float* __restrict__ Wv,
                                              u16* __restrict__ Q, u16* __restrict__ K,
                                              u16* __restrict__ V) {
    int t = threadIdx.x;
    int wv = t >> 6, lane = t & 63, c15 = lane & 15, quad = lane >> 4;
    int mat = blockIdx.x >> 9;            // 0=Q 1=K 2=V
    int sub = blockIdx.x & 511;
    int b = sub >> 7;
    int nb = (sub & 127) * 32;
    const float* xb = x + ((size_t)b << 20);
    const float* W = (mat == 0) ? Wq : (mat == 1) ? Wk : Wv;
    float s = (mat == 0) ? (0.125f * LOG2E) : 1.0f;

    // A-frags straight from global: A[m=n_local][k=c]
    v8s Af[2][8];
#pragma unroll
    for (int nt = 0; nt < 2; ++nt) {
        const float* px = xb + nb + nt * 16 + c15 + (size_t)quad * 8 * 4096;
#pragma unroll
        for (int kc = 0; kc < 8; ++kc) {
            float f[8];
#pragma unroll
            for (int j = 0; j < 8; ++j)
                f[j] = px[((size_t)kc * 32 + j) * 4096];
            union { v8s s; u32 w[4]; } pk;
            pk.w[0] = pkbf(f[0], f[1]); pk.w[1] = pkbf(f[2], f[3]);
            pk.w[2] = pkbf(f[4], f[5]); pk.w[3] = pkbf(f[6], f[7]);
            Af[nt][kc] = pk.s;
        }
    }

    // B-frags from fp32 W inline: B[k=c][col=r], wave wv -> r-tile wv
    v8s Bf[8];
    {
        const float* wr = W + (size_t)(wv * 16 + c15) * 256 + quad * 8;
#pragma unroll
        for (int kc = 0; kc < 8; ++kc) {
            float4 a = *(const float4*)&wr[kc * 32];
            float4 c = *(const float4*)&wr[kc * 32 + 4];
            union { v8s s; u32 w[4]; } pk;
            pk.w[0] = pkbf(a.x * s, a.y * s); pk.w[1] = pkbf(a.z * s, a.w * s);
            pk.w[2] = pkbf(c.x * s, c.y * s); pk.w[3] = pkbf(c.z * s, c.w * s);
            Bf[kc] = pk.s;
        }
    }

#pragma unroll
    for (int nt = 0; nt < 2; ++nt) {
        v4f acc = {0.f, 0.f, 0.f, 0.f};
#pragma unroll
        for (int kc = 0; kc < 8; ++kc)
            acc = mfma16(Af[nt][kc], Bf[kc], acc);
        // C layout: row(n_local) = quad*4+g, col(r_local) = c15
        if (mat < 2) {
            u16* base = (mat == 0) ? Q : K;
            u16* dst = base + ((size_t)b << 18)
                     + (size_t)(nb + nt * 16 + quad * 4) * 64
                     + wv * 16 + c15;
#pragma unroll
            for (int g = 0; g < 4; ++g) dst[g * 64] = f2bf(acc[g]);
        } else {
            // V permuted: n = nb+nt*16+quad*4+g ; pos=(n&15)*4+((n>>4)&3)
            int hi2 = ((nb + nt * 16) >> 4) & 3;
            size_t base = ((size_t)b * 64 + wv * 16 + c15) * 4096
                        + (size_t)((nb + nt * 16) & ~63) + hi2;
#pragma unroll
            for (int g = 0; g < 4; ++g)
                V[base + (quad * 4 + g) * 4] = f2bf(acc[g]);
        }
    }
}

// ------------- kernel 2: flash attention, double-buffered, 1 barrier/iter ---
__global__ __launch_bounds__(256, 2) void k_flash(const u16* __restrict__ Q,
                                                  const u16* __restrict__ K,
                                                  const u16* __restrict__ V,
                                                  u16* __restrict__ OP,
                                                  float* __restrict__ Lb,
                                                  int sh) {
    __shared__ u16 Kl[2][64][72];    // K tile (m,r), double-buffered
    __shared__ u16 Vl[2][64][72];    // V tile (r, pos), double-buffered
    __shared__ u16 Pl[4][32][72];    // per-wave P: [row][pos]
    int t = threadIdx.x;
    int p = blockIdx.x & ((1u << sh) - 1);
    int tile = blockIdx.x >> sh;
    int b = tile >> 5;
    int n0 = (tile & 31) * 128;
    int wv = t >> 6;
    int lane = t & 63;
    int c15 = lane & 15;
    int quad = lane >> 4;
    int nw = n0 + wv * 32;
    const u16* Qb = Q + (size_t)b * NN * 64;
    const u16* Kb = K + (size_t)b * NN * 64;
    const u16* Vb = V + (size_t)b * 64 * NN;

    v8s Qa[2][2];
#pragma unroll
    for (int rg = 0; rg < 2; ++rg)
#pragma unroll
        for (int c2 = 0; c2 < 2; ++c2)
            Qa[rg][c2] = *(const v8s*)&Qb[(size_t)(nw + rg * 16 + c15) * 64 + c2 * 32 + quad * 8];

    v4f O[2][4];
    float ls[2][4];
#pragma unroll
    for (int rg = 0; rg < 2; ++rg)
#pragma unroll
        for (int g = 0; g < 4; ++g) {
            ls[rg][g] = 0.f;
#pragma unroll
            for (int cg = 0; cg < 4; ++cg) O[rg][cg][g] = 0.f;
        }

    int mlen = NN >> sh;
    int m0 = p * mlen;
    int iters = mlen >> 6;
    int srow = t >> 3, scol = (t & 7) * 8;

    // stage tile 0 into buffer 0
#pragma unroll
    for (int pass = 0; pass < 2; ++pass) {
        int rr = srow + pass * 32;
        *(v8s*)&Kl[0][rr][scol] = *(const v8s*)&Kb[(size_t)(m0 + rr) * 64 + scol];
        *(v8s*)&Vl[0][rr][scol] = *(const v8s*)&Vb[(size_t)rr * NN + m0 + scol];
    }
    __syncthreads();

    for (int it = 0; it < iters; ++it) {
        int cur = it & 1, nxt = cur ^ 1;

        // issue next tile's global loads first; latency hidden by compute
        v8s kn[2], vn[2];
        if (it + 1 < iters) {
            int mt = m0 + (it + 1) * 64;
#pragma unroll
            for (int pass = 0; pass < 2; ++pass) {
                int rr = srow + pass * 32;
                kn[pass] = *(const v8s*)&Kb[(size_t)(mt + rr) * 64 + scol];
                vn[pass] = *(const v8s*)&Vb[(size_t)rr * NN + mt + scol];
            }
        }

        v4f S[2][4];
#pragma unroll
        for (int rg = 0; rg < 2; ++rg)
#pragma unroll
            for (int s = 0; s < 4; ++s)
#pragma unroll
                for (int g = 0; g < 4; ++g) S[rg][s][g] = 0.f;
#pragma unroll
        for (int s = 0; s < 4; ++s)
#pragma unroll
            for (int c2 = 0; c2 < 2; ++c2) {
                v8s kb = *(const v8s*)&Kl[cur][s * 16 + c15][c2 * 32 + quad * 8];
                S[0][s] = mfma16(Qa[0][c2], kb, S[0][s]);
                S[1][s] = mfma16(Qa[1][c2], kb, S[1][s]);
            }

        // fixed-max softmax: P = 2^s ; packed writes to permuted columns
#pragma unroll
        for (int rg = 0; rg < 2; ++rg) {
            float E[4][4];
#pragma unroll
            for (int s = 0; s < 4; ++s)
#pragma unroll
                for (int g = 0; g < 4; ++g) {
                    float e = fexp2(S[rg][s][g]);
                    E[s][g] = e;
                    ls[rg][g] += e;
                }
#pragma unroll
            for (int g = 0; g < 4; ++g) {
                union { u16x4 v; u32 w[2]; } p2;
                p2.w[0] = pkbf(E[0][g], E[1][g]);
                p2.w[1] = pkbf(E[2][g], E[3][g]);
                *(u16x4*)&Pl[wv][rg * 16 + quad * 4 + g][c15 * 4] = p2.v;
            }
        }
        // per-wave LDS round-trip: lgkmcnt orders intra-wave, no barrier

        v8s Pa[2][2];
#pragma unroll
        for (int rg = 0; rg < 2; ++rg)
#pragma unroll
            for (int c2 = 0; c2 < 2; ++c2)
                Pa[rg][c2] = *(const v8s*)&Pl[wv][rg * 16 + c15][c2 * 32 + quad * 8];
#pragma unroll
        for (int cg = 0; cg < 4; ++cg)
#pragma unroll
            for (int c2 = 0; c2 < 2; ++c2) {
                v8s vb = *(const v8s*)&Vl[cur][cg * 16 + c15][c2 * 32 + quad * 8];
                O[0][cg] = mfma16(Pa[0][c2], vb, O[0][cg]);
                O[1][cg] = mfma16(Pa[1][c2], vb, O[1][cg]);
            }

        // commit next tile into the idle buffer, then one barrier
        if (it + 1 < iters) {
#pragma unroll
            for (int pass = 0; pass < 2; ++pass) {
                int rr = srow + pass * 32;
                *(v8s*)&Kl[nxt][rr][scol] = kn[pass];
                *(v8s*)&Vl[nxt][rr][scol] = vn[pass];
            }
        }
        __syncthreads();
    }

    u16* OPp = OP + (size_t)p * (NB * NN * 64) + (size_t)b * NN * 64;
#pragma unroll
    for (int rg = 0; rg < 2; ++rg)
#pragma unroll
        for (int cg = 0; cg < 4; ++cg)
#pragma unroll
            for (int g = 0; g < 4; ++g) {
                int n = nw + rg * 16 + quad * 4 + g;
                OPp[(size_t)n * 64 + cg * 16 + c15] = f2bf(O[rg][cg][g]);
            }
#pragma unroll
    for (int rg = 0; rg < 2; ++rg)
#pragma unroll
        for (int g = 0; g < 4; ++g) {
            float v = ls[rg][g];
#pragma unroll
            for (int off = 1; off <= 8; off <<= 1) v += __shfl_xor(v, off);
            ls[rg][g] = v;
        }
    if (c15 == 0) {
        float* Lp = Lb + (size_t)p * (NB * NN) + (size_t)b * NN;
#pragma unroll
        for (int rg = 0; rg < 2; ++rg)
#pragma unroll
            for (int g = 0; g < 4; ++g) {
                int n = nw + rg * 16 + quad * 4 + g;
                Lp[n] = ls[rg][g];
            }
    }
}

// ------------- kernel 3: merge splits + Wp MFMA projection + residual -------
#define OMP 72
__global__ __launch_bounds__(256) void k_proj(const u16* __restrict__ OP,
                                              const float* __restrict__ Lb,
                                              const float* __restrict__ Wp,
                                              const float* __restrict__ x,
                                              float* __restrict__ out,
                                              int nsp) {
    __shared__ u16 Om[16 * OMP];
    int t = threadIdx.x;
    int b = blockIdx.x >> 8;
    int n0 = (blockIdx.x & 255) * 16;

    {
        int n_l = t >> 4, r0 = (t & 15) * 4;
        size_t nidx = (size_t)b * NN + n0 + n_l;
        float o[4] = {0.f, 0.f, 0.f, 0.f};
        float l = 0.f;
        for (int p = 0; p < nsp; ++p) {
            u16x4 u = *(const u16x4*)&OP[((size_t)p * (NB * NN) + nidx) * 64 + r0];
#pragma unroll
            for (int j = 0; j < 4; ++j) o[j] += bf2f(u[j]);
            l += Lb[(size_t)p * (NB * NN) + nidx];
        }
        float inv = 1.0f / l;
        union { u16x4 v; u32 w[2]; } p2;
        p2.w[0] = pkbf(o[0] * inv, o[1] * inv);
        p2.w[1] = pkbf(o[2] * inv, o[3] * inv);
        *(u16x4*)&Om[n_l * OMP + r0] = p2.v;
    }
    __syncthreads();

    int lane = t & 63, wvv = t >> 6, c15 = lane & 15, quad = lane >> 4;
    v8s B0 = *(const v8s*)&Om[c15 * OMP + quad * 8];
    v8s B1 = *(const v8s*)&Om[c15 * OMP + 32 + quad * 8];
#pragma unroll
    for (int ct0 = 0; ct0 < 4; ++ct0) {
        int ct = wvv * 4 + ct0;
        // inline fp32 Wp -> bf16 A-frags: A[m=cout][k=r]
        const float* wr = Wp + (size_t)(ct * 16 + c15) * 64 + quad * 8;
        float4 wa = *(const float4*)&wr[0];
        float4 wb = *(const float4*)&wr[4];
        float4 wc = *(const float4*)&wr[32];
        float4 wd = *(const float4*)&wr[36];
        union { v8s s; u32 w[4]; } pa, pb;
        pa.w[0] = pkbf(wa.x, wa.y); pa.w[1] = pkbf(wa.z, wa.w);
        pa.w[2] = pkbf(wb.x, wb.y); pa.w[3] = pkbf(wb.z, wb.w);
        pb.w[0] = pkbf(wc.x, wc.y); pb.w[1] = pkbf(wc.z, wc.w);
        pb.w[2] = pkbf(wd.x, wd.y); pb.w[3] = pkbf(wd.z, wd.w);
        v4f acc = {0.f, 0.f, 0.f, 0.f};
        acc = mfma16(pa.s, B0, acc);
        acc = mfma16(pb.s, B1, acc);
        size_t base = ((size_t)(b * 256 + ct * 16 + quad * 4)) * 4096 + n0 + c15;
#pragma unroll
        for (int g = 0; g < 4; ++g)
            out[base + (size_t)g * 4096] = acc[g] + x[base + (size_t)g * 4096];
    }
}

extern "C" void kernel_launch(void* const* d_in, const int* in_sizes, int n_in,
                              void* d_out, int out_size, void* d_ws, size_t ws_size,
                              hipStream_t stream) {
    const float* x  = (const float*)d_in[0];
    const float* Wq = (const float*)d_in[1];
    const float* Wk = (const float*)d_in[2];
    const float* Wv = (const float*)d_in[3];
    const float* Wp = (const float*)d_in[4];
    float* out = (float*)d_out;
    char* ws = (char*)d_ws;

    int nsp = (ws_size >= (size_t)24 * 1024 * 1024) ? 8 : 4;
    int sh = (nsp == 8) ? 3 : 2;

    u16* Q   = (u16*)(ws);                                   // 2 MB
    u16* K   = (u16*)(ws + 2097152);                         // 2 MB
    u16* V   = (u16*)(ws + 2 * 2097152);                     // 2 MB
    u16* OP  = (u16*)(ws + 3 * 2097152);                     // nsp*2 MB
    float* Lbuf = (float*)(ws + (size_t)(3 + nsp) * 2097152);

    k_qkvm<<<1536, 256, 0, stream>>>(x, Wq, Wk, Wv, Q, K, V);
    k_flash<<<NB * 32 * nsp, 256, 0, stream>>>(Q, K, V, OP, Lbuf, sh);
    k_proj<<<NB * 256, 256, 0, stream>>>(OP, Lbuf, Wp, x, out, nsp);
}